// Round 1
// baseline (267.521 us; speedup 1.0000x reference)
//
#include <hip/hip_runtime.h>

typedef __attribute__((ext_vector_type(8))) short bf16x8;
typedef __attribute__((ext_vector_type(16))) float f32x16;

#define LN_EPS 1e-5f

__device__ __forceinline__ unsigned short f2bf(float f) {
    unsigned u = __float_as_uint(f);
    unsigned r = (u + 0x7FFFu + ((u >> 16) & 1u)) >> 16;
    return (unsigned short)r;
}

// ---------------------------------------------------------------------------
// prep: build bf16 transposed weight images in workspace.
//   wt_lin [128][256]  = W_lin^T              (linear, read direct from global)
//   wt5 [5][128][128]  = {W1a,W1b,W1c,W2,W3}^T, XOR-swizzled k ^= (n&7)<<3
//                        (LDS image: staged linearly, read with same XOR)
// ---------------------------------------------------------------------------
__global__ void prep_weights(const float* __restrict__ W_lin,
                             const float* __restrict__ W1,
                             const float* __restrict__ W2,
                             const float* __restrict__ W3,
                             unsigned short* __restrict__ wt_lin,
                             unsigned short* __restrict__ wt5) {
    int i = blockIdx.x * blockDim.x + threadIdx.x;
    if (i < 128 * 256) {
        int n = i >> 8, k = i & 255;
        wt_lin[n * 256 + k] = f2bf(W_lin[k * 128 + n]);
    } else if (i < 128 * 256 + 5 * 128 * 128) {
        int j = i - 128 * 256;
        int m = j >> 14, r = j & 16383;
        int n = r >> 7, k = r & 127;
        float v;
        if (m < 3)       v = W1[(m * 128 + k) * 128 + n];
        else if (m == 3) v = W2[k * 128 + n];
        else             v = W3[k * 128 + n];
        int kk = k ^ ((n & 7) << 3);
        wt5[m * 16384 + n * 128 + kk] = f2bf(v);
    }
}

// ---------------------------------------------------------------------------
// atoms_gemm: atom_scalars(bf16)[N][128] = atom_features[N][256] @ W_lin
// 256 thr / 4 waves, 128 rows per block, mfma 32x32x16, no LDS.
// ---------------------------------------------------------------------------
__global__ void atoms_gemm(const float* __restrict__ af,
                           const unsigned short* __restrict__ wt_lin,
                           unsigned short* __restrict__ atoms_bf,
                           int Natoms) {
    const int wv = threadIdx.x >> 6, lane = threadIdx.x & 63;
    const int l31 = lane & 31, g8 = (lane >> 5) * 8, g4 = (lane >> 5) * 4;
    const int R = blockIdx.x * 128 + wv * 32;

    f32x16 acc[4];
#pragma unroll
    for (int f = 0; f < 4; ++f)
#pragma unroll
        for (int e = 0; e < 16; ++e) acc[f][e] = 0.0f;

    int arow = R + l31;
    if (arow >= Natoms) arow = Natoms - 1;
    const float* ap = af + (size_t)arow * 256;

#pragma unroll
    for (int ks = 0; ks < 16; ++ks) {
        const int k0 = ks * 16 + g8;
        float4 x0 = *(const float4*)(ap + k0);
        float4 x1 = *(const float4*)(ap + k0 + 4);
        bf16x8 a;
        a[0] = (short)f2bf(x0.x); a[1] = (short)f2bf(x0.y);
        a[2] = (short)f2bf(x0.z); a[3] = (short)f2bf(x0.w);
        a[4] = (short)f2bf(x1.x); a[5] = (short)f2bf(x1.y);
        a[6] = (short)f2bf(x1.z); a[7] = (short)f2bf(x1.w);
#pragma unroll
        for (int f = 0; f < 4; ++f) {
            bf16x8 b = *(const bf16x8*)(wt_lin + (32 * f + l31) * 256 + k0);
            acc[f] = __builtin_amdgcn_mfma_f32_32x32x16_bf16(a, b, acc[f], 0, 0, 0);
        }
    }

#pragma unroll
    for (int f = 0; f < 4; ++f) {
        const int col = 32 * f + l31;
#pragma unroll
        for (int r = 0; r < 16; ++r) {
            int row = R + (r & 3) + 8 * (r >> 2) + g4;
            if (row < Natoms) atoms_bf[(size_t)row * 128 + col] = f2bf(acc[f][r]);
        }
    }
}

// ---------------------------------------------------------------------------
// edge_mlp: fully fused gather -> 3-layer MLP -> residual -> LayerNorm
// 512 thr / 8 waves, 256 edges per block, wave-tile 32x128.
// LDS: W double-buffer 2x32KB + wave-private act 8x8KB = 128 KB.
// ---------------------------------------------------------------------------
__device__ __forceinline__ void zero4(f32x16* a) {
#pragma unroll
    for (int f = 0; f < 4; ++f)
#pragma unroll
        for (int e = 0; e < 16; ++e) a[f][e] = 0.0f;
}

// A from per-lane global row pointer (linear), B from swizzled LDS weights
__device__ __forceinline__ void chunk_globalA(const unsigned short* __restrict__ arow,
                                              const unsigned short* __restrict__ W,
                                              int l31, int g8, int sw, f32x16* acc) {
#pragma unroll
    for (int ks = 0; ks < 8; ++ks) {
        bf16x8 a = *(const bf16x8*)(arow + ks * 16 + g8);
#pragma unroll
        for (int f = 0; f < 4; ++f) {
            bf16x8 b = *(const bf16x8*)(W + (32 * f + l31) * 128 + ((ks * 16 + g8) ^ sw));
            acc[f] = __builtin_amdgcn_mfma_f32_32x32x16_bf16(a, b, acc[f], 0, 0, 0);
        }
    }
}

// A from wave-private swizzled LDS activations, B from swizzled LDS weights
__device__ __forceinline__ void chunk_ldsA(const unsigned short* __restrict__ actw,
                                           const unsigned short* __restrict__ W,
                                           int l31, int g8, int sw, f32x16* acc) {
#pragma unroll
    for (int ks = 0; ks < 8; ++ks) {
        bf16x8 a = *(const bf16x8*)(actw + l31 * 128 + ((ks * 16 + g8) ^ sw));
#pragma unroll
        for (int f = 0; f < 4; ++f) {
            bf16x8 b = *(const bf16x8*)(W + (32 * f + l31) * 128 + ((ks * 16 + g8) ^ sw));
            acc[f] = __builtin_amdgcn_mfma_f32_32x32x16_bf16(a, b, acc[f], 0, 0, 0);
        }
    }
}

__global__ __launch_bounds__(512, 2) void edge_mlp(
    const float* __restrict__ ef, const int* __restrict__ eidx,
    const unsigned short* __restrict__ atoms_bf,
    const unsigned short* __restrict__ wt5,
    const float* __restrict__ b1, const float* __restrict__ b2,
    const float* __restrict__ b3, const float* __restrict__ gamma_,
    const float* __restrict__ beta_, float* __restrict__ out, int E) {
    __shared__ unsigned short Wbuf[2][16384];  // 2 x 32 KB
    __shared__ unsigned short act[8][4096];    // 8 x 8 KB, wave-private

    const int tid = threadIdx.x;
    const int wv = tid >> 6, lane = tid & 63;
    const int l31 = lane & 31, g = lane >> 5, g8 = g * 8, g4 = g * 4;
    const int sw = (l31 & 7) << 3;
    const int R = blockIdx.x * 256 + wv * 32;

    // stage one 32KB weight matrix: linear global_load_lds, 512 thr x 16B x 4
    auto stage = [&](int buf, int mat) {
        const char* s = (const char*)(wt5 + mat * 16384);
        char* d = (char*)(&Wbuf[buf][0]);
        const int o = tid * 16;
#pragma unroll
        for (int i = 0; i < 4; ++i)
            __builtin_amdgcn_global_load_lds(
                (const __attribute__((address_space(1))) unsigned int*)(s + o + i * 8192),
                (__attribute__((address_space(3))) unsigned int*)(d + o + i * 8192),
                16, 0, 0);
    };

    int e_l = R + l31;
    if (e_l >= E) e_l = E - 1;
    const int dstI = eidx[e_l];
    const int srcI = eidx[E + e_l];

    float b1c[4], b2c[4], b3c[4], gc[4], bc[4];
#pragma unroll
    for (int f = 0; f < 4; ++f) {
        const int c = 32 * f + l31;
        b1c[f] = b1[c]; b2c[f] = b2[c]; b3c[f] = b3[c];
        gc[f] = gamma_[c]; bc[f] = beta_[c];
    }

    unsigned short* actw = &act[wv][0];
    f32x16 acc[4];

    stage(0, 0);                 // Wt1a
    __syncthreads();

    zero4(acc);
    // ---- phase 0: dst gather chunk (W = Wt1a), prefetch Wt1b
    stage(1, 1);
    chunk_globalA(atoms_bf + (size_t)dstI * 128, &Wbuf[0][0], l31, g8, sw, acc);
    __syncthreads();

    // ---- phase 1: src gather chunk (W = Wt1b), prefetch Wt1c
    stage(0, 2);
    chunk_globalA(atoms_bf + (size_t)srcI * 128, &Wbuf[1][0], l31, g8, sw, acc);
    __syncthreads();

    // ---- phase 2: edge_features chunk (W = Wt1c), prefetch Wt2
    stage(1, 3);
    {
        const float* erow = ef + (size_t)e_l * 128;
        const unsigned short* W = &Wbuf[0][0];
#pragma unroll
        for (int ks = 0; ks < 8; ++ks) {
            const int k0 = ks * 16 + g8;
            float4 x0 = *(const float4*)(erow + k0);
            float4 x1 = *(const float4*)(erow + k0 + 4);
            bf16x8 a;
            a[0] = (short)f2bf(x0.x); a[1] = (short)f2bf(x0.y);
            a[2] = (short)f2bf(x0.z); a[3] = (short)f2bf(x0.w);
            a[4] = (short)f2bf(x1.x); a[5] = (short)f2bf(x1.y);
            a[6] = (short)f2bf(x1.z); a[7] = (short)f2bf(x1.w);
#pragma unroll
            for (int f = 0; f < 4; ++f) {
                bf16x8 b = *(const bf16x8*)(W + (32 * f + l31) * 128 + (k0 ^ sw));
                acc[f] = __builtin_amdgcn_mfma_f32_32x32x16_bf16(a, b, acc[f], 0, 0, 0);
            }
        }
    }
    // L1 epilogue: bias + relu -> bf16 act (wave-private, swizzled)
#pragma unroll
    for (int f = 0; f < 4; ++f) {
        const int col = 32 * f + l31;
#pragma unroll
        for (int r = 0; r < 16; ++r) {
            const int row = (r & 3) + 8 * (r >> 2) + g4;
            float v = fmaxf(acc[f][r] + b1c[f], 0.0f);
            actw[row * 128 + (col ^ ((row & 7) << 3))] = f2bf(v);
        }
    }
    __syncthreads();

    // ---- phase 3: layer 2 (W = Wt2), prefetch Wt3
    stage(0, 4);
    zero4(acc);
    chunk_ldsA(actw, &Wbuf[1][0], l31, g8, sw, acc);
    // L2 epilogue: bias + relu -> act
#pragma unroll
    for (int f = 0; f < 4; ++f) {
        const int col = 32 * f + l31;
#pragma unroll
        for (int r = 0; r < 16; ++r) {
            const int row = (r & 3) + 8 * (r >> 2) + g4;
            float v = fmaxf(acc[f][r] + b2c[f], 0.0f);
            actw[row * 128 + (col ^ ((row & 7) << 3))] = f2bf(v);
        }
    }
    __syncthreads();

    // ---- phase 4: layer 3 (W = Wt3)
    zero4(acc);
    chunk_ldsA(actw, &Wbuf[0][0], l31, g8, sw, acc);

    // ---- epilogue: bias + f32 residual + LayerNorm + store
    float s_[16], q_[16];
#pragma unroll
    for (int r = 0; r < 16; ++r) { s_[r] = 0.0f; q_[r] = 0.0f; }
#pragma unroll
    for (int f = 0; f < 4; ++f) {
#pragma unroll
        for (int r = 0; r < 16; ++r) {
            int row = R + (r & 3) + 8 * (r >> 2) + g4;
            if (row >= E) row = E - 1;
            float v = acc[f][r] + b3c[f] + ef[(size_t)row * 128 + 32 * f + l31];
            acc[f][r] = v;
            s_[r] += v;
            q_[r] += v * v;
        }
    }
#pragma unroll
    for (int m = 1; m <= 16; m <<= 1) {
#pragma unroll
        for (int r = 0; r < 16; ++r) {
            s_[r] += __shfl_xor(s_[r], m, 64);
            q_[r] += __shfl_xor(q_[r], m, 64);
        }
    }
#pragma unroll
    for (int r = 0; r < 16; ++r) {
        const float mu = s_[r] * (1.0f / 128.0f);
        const float var = q_[r] * (1.0f / 128.0f) - mu * mu;
        const float rs = rsqrtf(var + LN_EPS);
        const int row = R + (r & 3) + 8 * (r >> 2) + g4;
        if (row < E) {
#pragma unroll
            for (int f = 0; f < 4; ++f)
                out[(size_t)row * 128 + 32 * f + l31] =
                    (acc[f][r] - mu) * rs * gc[f] + bc[f];
        }
    }
}

// ---------------------------------------------------------------------------
extern "C" void kernel_launch(void* const* d_in, const int* in_sizes, int n_in,
                              void* d_out, int out_size, void* d_ws, size_t ws_size,
                              hipStream_t stream) {
    const float* atom_features = (const float*)d_in[0];
    const float* edge_features = (const float*)d_in[1];
    const int* edge_index = (const int*)d_in[2];
    const float* W_lin = (const float*)d_in[3];
    const float* W1 = (const float*)d_in[4];
    const float* b1 = (const float*)d_in[5];
    const float* W2 = (const float*)d_in[6];
    const float* b2 = (const float*)d_in[7];
    const float* W3 = (const float*)d_in[8];
    const float* b3 = (const float*)d_in[9];
    const float* gamma_ = (const float*)d_in[10];
    const float* beta_ = (const float*)d_in[11];
    float* out = (float*)d_out;

    const int Natoms = in_sizes[0] / 256;
    const int E = in_sizes[1] / 128;

    unsigned short* atoms_bf = (unsigned short*)d_ws;
    unsigned short* wt_lin = atoms_bf + (size_t)Natoms * 128;
    unsigned short* wt5 = wt_lin + 128 * 256;

    const int prep_items = 128 * 256 + 5 * 128 * 128;
    prep_weights<<<(prep_items + 255) / 256, 256, 0, stream>>>(W_lin, W1, W2, W3,
                                                               wt_lin, wt5);
    atoms_gemm<<<(Natoms + 127) / 128, 256, 0, stream>>>(atom_features, wt_lin,
                                                         atoms_bf, Natoms);
    edge_mlp<<<(E + 255) / 256, 512, 0, stream>>>(edge_features, edge_index,
                                                  atoms_bf, wt5, b1, b2, b3,
                                                  gamma_, beta_, out, E);
}